// Round 1
// baseline (311.480 us; speedup 1.0000x reference)
//
#include <hip/hip_runtime.h>

// NURBS surface eval:
//   B=64 batches, ctrl grid 64x64 of (x,y,z,w), cubic (P=Q=3), OUT=512x512.
//   surf[b,U,V,:] = sum_{l,r} Nu[U,l]*Nv[V,r] * ctrl[b, iu[U,l], iv[V,r], :]
//   out = surf.xyz / surf.w
// Write-BW-bound: 201 MB output. One thread per output point; V along
// threadIdx.x for dense coalesced stores.

#define OUTDIM 512
#define CTRL_M 64
#define CTRL_N 64

__global__ __launch_bounds__(256) void surf_eval_kernel(
    const float* __restrict__ ctrl,   // [B,64,64,4]
    const float* __restrict__ Nu,     // [512,4]
    const float* __restrict__ Nv,     // [512,4]
    const int*   __restrict__ iu,     // [512,4]
    const int*   __restrict__ iv,     // [512,4]
    float*       __restrict__ out)    // [B,512,512,3]
{
    const int blk = blockIdx.x;
    const int V = ((blk & 1) << 8) | threadIdx.x;   // 0..511
    const int U = (blk >> 1) & (OUTDIM - 1);        // 0..511
    const int b = blk >> 10;                        // 0..63

    // Block-uniform (U-dependent) — scalar-cache friendly.
    const float4 nu  = *(const float4*)(Nu + U * 4);
    const int4   iu4 = *(const int4*)(iu + U * 4);
    // Per-lane (V-dependent).
    const float4 nv  = *(const float4*)(Nv + V * 4);
    const int4   iv4 = *(const int4*)(iv + V * 4);

    const float* cb = ctrl + (size_t)b * (CTRL_M * CTRL_N * 4);

    const float nus[4] = {nu.x, nu.y, nu.z, nu.w};
    const int   ius[4] = {iu4.x, iu4.y, iu4.z, iu4.w};
    const float nvs[4] = {nv.x, nv.y, nv.z, nv.w};
    const int   ivs[4] = {iv4.x, iv4.y, iv4.z, iv4.w};

    float ax = 0.f, ay = 0.f, az = 0.f, aw = 0.f;

#pragma unroll
    for (int l = 0; l < 4; ++l) {
        const float* row = cb + (size_t)ius[l] * (CTRL_N * 4);
        const float wl = nus[l];
#pragma unroll
        for (int r = 0; r < 4; ++r) {
            const float4 p = *(const float4*)(row + ivs[r] * 4);
            const float w = wl * nvs[r];
            ax = fmaf(w, p.x, ax);
            ay = fmaf(w, p.y, ay);
            az = fmaf(w, p.z, az);
            aw = fmaf(w, p.w, aw);
        }
    }

    const float inv = 1.0f / aw;
    const size_t o = (((size_t)b * OUTDIM + U) * OUTDIM + V) * 3;
    out[o + 0] = ax * inv;
    out[o + 1] = ay * inv;
    out[o + 2] = az * inv;
}

extern "C" void kernel_launch(void* const* d_in, const int* in_sizes, int n_in,
                              void* d_out, int out_size, void* d_ws, size_t ws_size,
                              hipStream_t stream) {
    const float* ctrl = (const float*)d_in[0];
    const float* Nu   = (const float*)d_in[1];
    const float* Nv   = (const float*)d_in[2];
    const int*   iu   = (const int*)d_in[3];
    const int*   iv   = (const int*)d_in[4];
    float* out = (float*)d_out;

    // grid: B * 512 (U) * 2 (V halves) = 65536 blocks of 256 threads
    const int nblocks = 64 * OUTDIM * 2;
    surf_eval_kernel<<<nblocks, 256, 0, stream>>>(ctrl, Nu, Nv, iu, iv, out);
}

// Round 2
// 204.420 us; speedup vs baseline: 1.5237x; 1.5237x over previous
//
#include <hip/hip_runtime.h>

// NURBS surface eval, two-stage separable form.
//   Stage 1 (per block = one batch b x 8 U-rows): contract over u into LDS:
//     rows[u][n][0:4] = sum_l Nu[U,l] * ctrl[b, iu[U,l], n, 0:4]   (n = 0..63)
//   Stage 2: each thread owns V (2 halves of 512), loops u=0..7:
//     surf = sum_r Nv[V,r] * rows[u][iv[V,r]];  out = surf.xyz / surf.w
// This cuts per-output global loads 32x (16 float4 -> 0.5), moving the
// gather onto the LDS/DS pipe; stores (201 MB) become the floor.

#define OUTDIM 512
#define CTRL_N 64
#define TU 8

__global__ __launch_bounds__(256) void surf_eval_kernel(
    const float* __restrict__ ctrl,   // [B,64,64,4]
    const float* __restrict__ Nu,     // [512,4]
    const float* __restrict__ Nv,     // [512,4]
    const int*   __restrict__ iu,     // [512,4]
    const int*   __restrict__ iv,     // [512,4]
    float*       __restrict__ out)    // [B,512,512,3]
{
    __shared__ float4 rows[TU * CTRL_N];   // 8 KB

    const int blk = blockIdx.x;
    const int b  = blk >> 6;               // 0..63
    const int U0 = (blk & 63) * TU;        // 0,8,...,504
    const int t  = threadIdx.x;

    // ---------- stage 1: u-contraction into LDS ----------
    {
        const int u  = t >> 5;             // 0..7
        const int n0 = t & 31;             // 0..31 (+32 for second point)
        const int U  = U0 + u;
        const float4 nu  = *(const float4*)(Nu + U * 4);
        const int4   iu4 = *(const int4*)(iu + U * 4);
        const float* cb = ctrl + (size_t)b * (64 * 64 * 4);
        const float* r0 = cb + (size_t)iu4.x * (CTRL_N * 4);
        const float* r1 = cb + (size_t)iu4.y * (CTRL_N * 4);
        const float* r2 = cb + (size_t)iu4.z * (CTRL_N * 4);
        const float* r3 = cb + (size_t)iu4.w * (CTRL_N * 4);

#pragma unroll
        for (int k = 0; k < 2; ++k) {
            const int n = n0 + 32 * k;
            const float4 p0 = *(const float4*)(r0 + n * 4);
            const float4 p1 = *(const float4*)(r1 + n * 4);
            const float4 p2 = *(const float4*)(r2 + n * 4);
            const float4 p3 = *(const float4*)(r3 + n * 4);
            float4 acc;
            acc.x = nu.x * p0.x + nu.y * p1.x + nu.z * p2.x + nu.w * p3.x;
            acc.y = nu.x * p0.y + nu.y * p1.y + nu.z * p2.y + nu.w * p3.y;
            acc.z = nu.x * p0.z + nu.y * p1.z + nu.z * p2.z + nu.w * p3.z;
            acc.w = nu.x * p0.w + nu.y * p1.w + nu.z * p2.w + nu.w * p3.w;
            rows[u * CTRL_N + n] = acc;
        }
    }
    __syncthreads();

    // ---------- stage 2: v-contraction from LDS ----------
    // Thread t handles V = t and V = t + 256.
    const float4 nvA = *(const float4*)(Nv + t * 4);
    const int4   ivA = *(const int4*)(iv + t * 4);
    const float4 nvB = *(const float4*)(Nv + (t + 256) * 4);
    const int4   ivB = *(const int4*)(iv + (t + 256) * 4);

    const size_t obase = ((size_t)b * OUTDIM + U0) * OUTDIM;

#pragma unroll
    for (int u = 0; u < TU; ++u) {
        const float4* ru = rows + u * CTRL_N;

        // half A: V = t
        {
            const float4 q0 = ru[ivA.x];
            const float4 q1 = ru[ivA.y];
            const float4 q2 = ru[ivA.z];
            const float4 q3 = ru[ivA.w];
            float sx = nvA.x * q0.x + nvA.y * q1.x + nvA.z * q2.x + nvA.w * q3.x;
            float sy = nvA.x * q0.y + nvA.y * q1.y + nvA.z * q2.y + nvA.w * q3.y;
            float sz = nvA.x * q0.z + nvA.y * q1.z + nvA.z * q2.z + nvA.w * q3.z;
            float sw = nvA.x * q0.w + nvA.y * q1.w + nvA.z * q2.w + nvA.w * q3.w;
            const float inv = __builtin_amdgcn_rcpf(sw);
            const size_t o = (obase + (size_t)u * OUTDIM + t) * 3;
            out[o + 0] = sx * inv;
            out[o + 1] = sy * inv;
            out[o + 2] = sz * inv;
        }
        // half B: V = t + 256
        {
            const float4 q0 = ru[ivB.x];
            const float4 q1 = ru[ivB.y];
            const float4 q2 = ru[ivB.z];
            const float4 q3 = ru[ivB.w];
            float sx = nvB.x * q0.x + nvB.y * q1.x + nvB.z * q2.x + nvB.w * q3.x;
            float sy = nvB.x * q0.y + nvB.y * q1.y + nvB.z * q2.y + nvB.w * q3.y;
            float sz = nvB.x * q0.z + nvB.y * q1.z + nvB.z * q2.z + nvB.w * q3.z;
            float sw = nvB.x * q0.w + nvB.y * q1.w + nvB.z * q2.w + nvB.w * q3.w;
            const float inv = __builtin_amdgcn_rcpf(sw);
            const size_t o = (obase + (size_t)u * OUTDIM + t + 256) * 3;
            out[o + 0] = sx * inv;
            out[o + 1] = sy * inv;
            out[o + 2] = sz * inv;
        }
    }
}

extern "C" void kernel_launch(void* const* d_in, const int* in_sizes, int n_in,
                              void* d_out, int out_size, void* d_ws, size_t ws_size,
                              hipStream_t stream) {
    const float* ctrl = (const float*)d_in[0];
    const float* Nu   = (const float*)d_in[1];
    const float* Nv   = (const float*)d_in[2];
    const int*   iu   = (const int*)d_in[3];
    const int*   iv   = (const int*)d_in[4];
    float* out = (float*)d_out;

    // grid: 64 batches x 64 U-tiles (of 8 rows) = 4096 blocks of 256 threads
    const int nblocks = 64 * (OUTDIM / TU);
    surf_eval_kernel<<<nblocks, 256, 0, stream>>>(ctrl, Nu, Nv, iu, iv, out);
}